// Round 4
// baseline (3509.371 us; speedup 1.0000x reference)
//
#include <hip/hip_runtime.h>
#include <hip/hip_bf16.h>

#define B_   32
#define T_   512
#define H_   1024
#define L_   256
#define V_   13
#define G4H  4096
#define KHL  1280   // H + L

typedef float f32x4 __attribute__((ext_vector_type(4)));
typedef short s16x8 __attribute__((ext_vector_type(8)));
typedef unsigned short u16;
typedef unsigned int   u32;

// ---------------- ws layout (bytes) ----------------
// Ax  : u16 [1026][16384]    @ 0           (33,619,968)  h chain, MFMA frag layout
// Bf  : u16 [4,194,304]      @ 33,619,968  (8,388,608)   W_hh A-fragments
// Bf2 : u16 [1,310,720]      @ 42,008,576  (2,621,440)   Wnl  B-fragments
// Az  : u16 [2][4096]        @ 44,630,016  (16,384)      latent frag layout
// bar : int [128]            @ 44,646,400  (512)         2 group counters
// mid : u16 [16384][1024]    @ 44,646,912  (33,554,432)
//   Gx (f32[57344]) and tok (u16[16384]) overlay mid (read only in k_recur).
#define OFF_BF   33619968u
#define OFF_BF2  42008576u
#define OFF_AZ   44630016u
#define OFF_BAR  44646400u
#define OFF_MID  44646912u
#define OFF_GX   OFF_MID                  // 229,376 B  = [jg][14][4] f32
#define OFF_TOK  (OFF_MID + 229376u)      //  32,768 B

__device__ __forceinline__ u16 f2bf(float f) {
    union { float f; u32 u; } v; v.f = f;
    u32 u = v.u;
    u32 r = (u + 0x7fffu + ((u >> 16) & 1u)) >> 16;   // RNE
    return (u16)r;
}
__device__ __forceinline__ float bf2f(u16 h) {
    union { u32 u; float f; } v; v.u = ((u32)h) << 16;
    return v.f;
}
__device__ __forceinline__ float sigm_(float x) {
    x = fminf(fmaxf(x, -30.f), 30.f);
    return 1.f / (1.f + __expf(-x));
}
__device__ __forceinline__ float tanh_(float x) {
    x = fminf(fmaxf(x, -15.f), 15.f);
    float e = __expf(2.f * x);
    return (e - 1.f) / (e + 1.f);
}

// fragment position of (lane-dim index bl, k) within a 16384-u16 slab
// (identical for MFMA A and B operands of 16x16x32)
__device__ __forceinline__ u32 afrag_pos(int bl, int k) {
    return (u32)((k >> 5) * 512 + ((bl | (((k >> 3) & 3) << 4)) << 3) + (k & 7));
}

// ---------------------------------------------------------------------------
__global__ __launch_bounds__(256) void k_init_misc(
        const float* __restrict__ latent, const float* __restrict__ Wz,
        const float* __restrict__ bz,
        u16* __restrict__ Ax, u16* __restrict__ Az, int* __restrict__ bar) {
    int gid = blockIdx.x * 256 + threadIdx.x;          // [0, 32768)
    int b = gid >> 10, j = gid & 1023;
    const float* lrow = latent + b * L_;
    const float* wrow = Wz + j * L_;
    float acc = bz[j];
    #pragma unroll 4
    for (int l = 0; l < L_; ++l) acc += lrow[l] * wrow[l];
    Ax[(b >> 4) * 16384 + afrag_pos(b & 15, j)] = f2bf(fmaxf(acc, 0.f));
    if (gid < B_ * L_) {
        int bb = gid >> 8, l = gid & 255;
        Az[(bb >> 4) * 4096 + afrag_pos(bb & 15, l)] = f2bf(latent[gid]);
    }
    if (gid == 0) { bar[0] = 0; bar[64] = 0; }
}

// Gx[jg][t][gg] (t in [0,14), gg gate): W_ih[gg*H+jg][t] + b_ih + b_hh ; t=13 -> bias only
__global__ __launch_bounds__(256) void k_init_gx(
        const float* __restrict__ W_ih, const float* __restrict__ b_ih,
        const float* __restrict__ b_hh, float* __restrict__ Gx) {
    int row = blockIdx.x * 256 + threadIdx.x;          // [0,4096)
    if (row >= G4H) return;
    int gg = row >> 10, jg = row & 1023;
    float base = b_ih[row] + b_hh[row];
    float* d = Gx + (size_t)jg * 56;
    const float* wr = W_ih + (size_t)row * V_;
    #pragma unroll
    for (int t = 0; t < V_; ++t) d[t * 4 + gg] = base + wr[t];
    d[13 * 4 + gg] = base;
}

// tok[s*32+b] = one-hot index of seq[b,s,:] (13 if all-zero start row)
__global__ __launch_bounds__(256) void k_init_tok(
        const float* __restrict__ seq, u16* __restrict__ tok) {
    int gid = blockIdx.x * 256 + threadIdx.x;          // [0,16384)
    int s = gid >> 5, b = gid & 31;
    const float* r = seq + ((size_t)b * T_ + s) * V_;
    int t = 13;
    #pragma unroll
    for (int v = 0; v < V_; ++v) if (r[v] > 0.5f) t = v;
    tok[gid] = (u16)t;
}

// W_hh -> MFMA A-fragments. Tile col u = jj*4 + gate  (so C rows quad*4+r give
// all 4 gates of jj=quad in acc[r]). idx = (nt<<14)|(kc<<9)|(lane<<3)|jv.
// u = lane&15 -> gate = u&3, jj = u>>2 ; W row = gate*H + nt*4 + jj.
__global__ __launch_bounds__(256) void k_init_wfrag(
        const float* __restrict__ W_hh, u16* __restrict__ Bf) {
    int base = blockIdx.x * 256 + threadIdx.x;         // 2048 blocks
    #pragma unroll
    for (int i = 0; i < 8; ++i) {
        int idx = base + i * 524288;                   // [0, 4194304)
        int jv   = idx & 7;
        int lane = (idx >> 3) & 63;
        int kc   = (idx >> 9) & 31;
        int nt   = idx >> 14;
        int u = lane & 15;
        int row = (u & 3) * H_ + nt * 4 + (u >> 2);
        int k = kc * 32 + (lane >> 4) * 8 + jv;
        Bf[idx] = f2bf(W_hh[row * H_ + k]);
    }
}

__global__ __launch_bounds__(256) void k_init_wfrag2(
        const float* __restrict__ Wnl, u16* __restrict__ Bf2) {
    int idx = blockIdx.x * 256 + threadIdx.x;
    for (; idx < 1310720; idx += 524288) {
        int jv   = idx & 7;
        int lane = (idx >> 3) & 63;
        int q    = idx >> 9;                           // nt2*40 + kc
        int kc   = q % 40;
        int nt2  = q / 40;
        int n = nt2 * 16 + (lane & 15);
        int k = kc * 32 + (lane >> 4) * 8 + jv;
        Bf2[idx] = f2bf(Wnl[n * KHL + k]);
    }
}

// ---------------------------------------------------------------------------
// Persistent LSTM recurrence. 64 blocks x 512 thr (8 waves); mt = bid&1 is the
// 16-batch group (independent counter). Per step: stage -> sync -> MFMA
// (A = W_hh regs, B = h LDS) -> gates in acc[] directly -> update -> store ->
// sync (drains vmcnt) -> tid0 arrival -> all waves poll monotone counter.
__global__ __launch_bounds__(512, 2) void k_recur(
        const u16* __restrict__ tokbuf, const float* __restrict__ Gx,
        const u16* __restrict__ Bf, u16* __restrict__ Ax,
        int* __restrict__ bar) {
    __shared__ u32 AhD[8192];             // 32 KB h slab (frag layout)
    int tid = threadIdx.x;
    int bid = blockIdx.x;
    int mt = bid & 1;
    int w = tid >> 6, L = tid & 63;
    int nt = (bid >> 1) * 8 + w;          // [0,256)
    int lm = L & 15, quad = L >> 4;

    // one-time: W_hh A-fragments into registers (128 VGPR target)
    s16x8 afr[32];
    {
        const u16* bfp = Bf + (size_t)nt * 16384 + L * 8;
        #pragma unroll
        for (int kc = 0; kc < 32; ++kc)
            afr[kc] = *reinterpret_cast<const s16x8*>(bfp + kc * 512);
    }
    int jg = nt * 4 + quad;               // this lane's output column
    int b = mt * 16 + lm;                 // this lane's batch
    const float* gxp = Gx + (size_t)jg * 56;
    u32 posu16 = (u32)((nt >> 3) * 512 + ((lm | (((nt >> 1) & 3) << 4)) << 3)
                       + (nt & 1) * 4 + quad);
    int* cnt = bar + mt * 64;
    u32* AxD = (u32*)Ax;
    float c = 0.f;

    for (int s = 0; s < T_; ++s) {
        // stage slab s (this mt) from LLC (relaxed agent loads bypass L1/L2)
        const u32* src = AxD + ((size_t)s * 2 + mt) * 8192;
        #pragma unroll
        for (int k = 0; k < 16; ++k)
            AhD[k * 512 + tid] = __hip_atomic_load(src + k * 512 + tid,
                __ATOMIC_RELAXED, __HIP_MEMORY_SCOPE_AGENT);
        __syncthreads();

        // gates tile: A = W frags (regs), B = h frags (LDS); 4 indep chains
        f32x4 a0 = {0.f,0.f,0.f,0.f}, a1 = {0.f,0.f,0.f,0.f};
        f32x4 a2 = {0.f,0.f,0.f,0.f}, a3 = {0.f,0.f,0.f,0.f};
        const u16* hp = (const u16*)AhD + L * 8;
        #pragma unroll
        for (int kc = 0; kc < 32; kc += 4) {
            s16x8 h0 = *reinterpret_cast<const s16x8*>(hp + kc * 512);
            s16x8 h1 = *reinterpret_cast<const s16x8*>(hp + (kc + 1) * 512);
            s16x8 h2 = *reinterpret_cast<const s16x8*>(hp + (kc + 2) * 512);
            s16x8 h3 = *reinterpret_cast<const s16x8*>(hp + (kc + 3) * 512);
            a0 = __builtin_amdgcn_mfma_f32_16x16x32_bf16(afr[kc],     h0, a0, 0, 0, 0);
            a1 = __builtin_amdgcn_mfma_f32_16x16x32_bf16(afr[kc + 1], h1, a1, 0, 0, 0);
            a2 = __builtin_amdgcn_mfma_f32_16x16x32_bf16(afr[kc + 2], h2, a2, 0, 0, 0);
            a3 = __builtin_amdgcn_mfma_f32_16x16x32_bf16(afr[kc + 3], h3, a3, 0, 0, 0);
        }
        // acc[r] = gate r (i,f,g,o) for (b, jg) — no transpose needed
        int tok = tokbuf[s * 32 + b];
        float4 gx4 = *reinterpret_cast<const float4*>(gxp + tok * 4);
        float gi = a0[0] + a1[0] + a2[0] + a3[0] + gx4.x;
        float gf = a0[1] + a1[1] + a2[1] + a3[1] + gx4.y;
        float gg = a0[2] + a1[2] + a2[2] + a3[2] + gx4.z;
        float go = a0[3] + a1[3] + a2[3] + a3[3] + gx4.w;
        float ig = sigm_(gi), fg = sigm_(gf);
        float gt = tanh_(gg), og = sigm_(go);
        c = fg * c + ig * gt;
        float hv = og * tanh_(c);

        // write h(s+1): pack 2 bf16/dword, relaxed agent store -> LLC
        u32 bits = (u32)f2bf(hv);
        u32 other = (u32)(u16)__shfl_xor((int)bits, 16);
        if (!(quad & 1)) {
            u32 word = bits | (other << 16);
            __hip_atomic_store(
                AxD + ((size_t)(s + 1) * 2 + mt) * 8192 + (posu16 >> 1),
                word, __ATOMIC_RELAXED, __HIP_MEMORY_SCOPE_AGENT);
        }
        __syncthreads();                  // drains every wave's vmcnt

        if (s == T_ - 1) break;           // nothing to wait for after last step
        if (tid == 0)
            __hip_atomic_fetch_add(cnt, 1, __ATOMIC_RELAXED,
                                   __HIP_MEMORY_SCOPE_AGENT);
        int target = 32 * (s + 1);
        while (__hip_atomic_load(cnt, __ATOMIC_RELAXED,
                                 __HIP_MEMORY_SCOPE_AGENT) < target)
            __builtin_amdgcn_s_sleep(1);
        asm volatile("" ::: "memory");    // compiler-only ordering guard
    }
}

// ---------------------------------------------------------------------------
// mid = relu(feat @ Wnl^T + bnl) — A/B frags straight from global, no LDS.
__global__ __launch_bounds__(256) void k_gemm1(
        const u16* __restrict__ Ax, const u16* __restrict__ Az,
        const u16* __restrict__ Bf2, const float* __restrict__ bnl,
        u16* __restrict__ mid) {
    int tid = threadIdx.x;
    int nb = blockIdx.x;                  // [0,16)
    int mb = blockIdx.y;                  // [0,128)
    int w = tid >> 6, L = tid & 63;
    int lm = L & 15, quad = L >> 4;
    int mti0 = mb * 8 + w * 2;
    const u16* a0p = Ax + ((size_t)mti0 + 2) * 16384 + L * 8;
    const u16* a1p = a0p + 16384;
    const u16* az0 = Az + L * 8;
    const u16* az1 = az0 + 4096;
    const u16* bp = Bf2 + (size_t)(nb * 4) * 40 * 512 + L * 8;

    f32x4 acc[2][4];
    #pragma unroll
    for (int a = 0; a < 2; ++a)
        #pragma unroll
        for (int n = 0; n < 4; ++n) acc[a][n] = (f32x4){0.f, 0.f, 0.f, 0.f};

    #pragma unroll 4
    for (int kc = 0; kc < 32; ++kc) {
        s16x8 a0 = *reinterpret_cast<const s16x8*>(a0p + kc * 512);
        s16x8 a1 = *reinterpret_cast<const s16x8*>(a1p + kc * 512);
        #pragma unroll
        for (int n4 = 0; n4 < 4; ++n4) {
            s16x8 bv = *reinterpret_cast<const s16x8*>(bp + ((size_t)n4 * 40 + kc) * 512);
            acc[0][n4] = __builtin_amdgcn_mfma_f32_16x16x32_bf16(a0, bv, acc[0][n4], 0, 0, 0);
            acc[1][n4] = __builtin_amdgcn_mfma_f32_16x16x32_bf16(a1, bv, acc[1][n4], 0, 0, 0);
        }
    }
    #pragma unroll
    for (int kc2 = 0; kc2 < 8; ++kc2) {
        s16x8 a0 = *reinterpret_cast<const s16x8*>(az0 + kc2 * 512);
        s16x8 a1 = *reinterpret_cast<const s16x8*>(az1 + kc2 * 512);
        #pragma unroll
        for (int n4 = 0; n4 < 4; ++n4) {
            s16x8 bv = *reinterpret_cast<const s16x8*>(bp + ((size_t)n4 * 40 + 32 + kc2) * 512);
            acc[0][n4] = __builtin_amdgcn_mfma_f32_16x16x32_bf16(a0, bv, acc[0][n4], 0, 0, 0);
            acc[1][n4] = __builtin_amdgcn_mfma_f32_16x16x32_bf16(a1, bv, acc[1][n4], 0, 0, 0);
        }
    }
    #pragma unroll
    for (int mt2 = 0; mt2 < 2; ++mt2)
        #pragma unroll
        for (int n4 = 0; n4 < 4; ++n4)
            #pragma unroll
            for (int r = 0; r < 4; ++r) {
                int m = mb * 128 + w * 32 + mt2 * 16 + quad * 4 + r;
                int n = (nb * 4 + n4) * 16 + lm;
                float v = acc[mt2][n4][r] + bnl[n];
                mid[(size_t)m * H_ + n] = f2bf(fmaxf(v, 0.f));
            }
}

// ---------------------------------------------------------------------------
__global__ __launch_bounds__(256) void k_loss(
        const u16* __restrict__ mid, const float* __restrict__ Wout,
        const float* __restrict__ bout, const int* __restrict__ labels,
        const int* __restrict__ lengths, float* __restrict__ out) {
    int mrow = blockIdx.x;                // m = t*32 + b
    int b = mrow & 31, t = mrow >> 5;
    if (t >= lengths[b]) return;
    int tid = threadIdx.x;
    float p[V_];
    #pragma unroll
    for (int v = 0; v < V_; ++v) p[v] = 0.f;
    uint2 raw = *reinterpret_cast<const uint2*>(mid + (size_t)mrow * H_ + tid * 4);
    const u16* rs = (const u16*)&raw;
    float mv0 = bf2f(rs[0]), mv1 = bf2f(rs[1]), mv2 = bf2f(rs[2]), mv3 = bf2f(rs[3]);
    #pragma unroll
    for (int v = 0; v < V_; ++v) {
        float4 wv = *reinterpret_cast<const float4*>(Wout + v * H_ + tid * 4);
        p[v] = mv0 * wv.x + mv1 * wv.y + mv2 * wv.z + mv3 * wv.w;
    }
    #pragma unroll
    for (int off = 32; off > 0; off >>= 1)
        #pragma unroll
        for (int v = 0; v < V_; ++v) p[v] += __shfl_down(p[v], off);
    __shared__ float red[4][V_];
    int w = tid >> 6, L = tid & 63;
    if (L == 0)
        #pragma unroll
        for (int v = 0; v < V_; ++v) red[w][v] = p[v];
    __syncthreads();
    if (tid == 0) {
        float lg[V_]; float mx = -1e30f;
        #pragma unroll
        for (int v = 0; v < V_; ++v) {
            lg[v] = red[0][v] + red[1][v] + red[2][v] + red[3][v] + bout[v];
            mx = fmaxf(mx, lg[v]);
        }
        float se = 0.f;
        #pragma unroll
        for (int v = 0; v < V_; ++v) se += __expf(lg[v] - mx);
        float lse = mx + logf(se);
        int lab = labels[b * T_ + t];
        atomicAdd(&out[1 + b], lse - lg[lab]);
    }
}

__global__ void k_final(float* __restrict__ out) {
    float s = 0.f;
    for (int b = 0; b < B_; ++b) s += out[1 + b];
    out[0] = s;
}

// ---------------------------------------------------------------------------
extern "C" void kernel_launch(void* const* d_in, const int* in_sizes, int n_in,
                              void* d_out, int out_size, void* d_ws, size_t ws_size,
                              hipStream_t stream) {
    const float* seq    = (const float*)d_in[0];
    const float* latent = (const float*)d_in[1];
    const int*   labels = (const int*)d_in[2];
    const int*   lengths= (const int*)d_in[3];
    const float* W_ih   = (const float*)d_in[4];
    const float* W_hh   = (const float*)d_in[5];
    const float* b_ih   = (const float*)d_in[6];
    const float* b_hh   = (const float*)d_in[7];
    const float* Wz     = (const float*)d_in[8];
    const float* bz     = (const float*)d_in[9];
    const float* Wnl    = (const float*)d_in[10];
    const float* bnl    = (const float*)d_in[11];
    const float* Wout   = (const float*)d_in[12];
    const float* bout   = (const float*)d_in[13];

    char* ws = (char*)d_ws;
    u16*   Ax   = (u16*)(ws);
    u16*   Bf   = (u16*)(ws + OFF_BF);
    u16*   Bf2  = (u16*)(ws + OFF_BF2);
    u16*   Az   = (u16*)(ws + OFF_AZ);
    int*   bar  = (int*)(ws + OFF_BAR);
    u16*   mid  = (u16*)(ws + OFF_MID);
    float* Gx   = (float*)(ws + OFF_GX);
    u16*   tok  = (u16*)(ws + OFF_TOK);
    float* out  = (float*)d_out;

    hipMemsetAsync(d_out, 0, 33 * sizeof(float), stream);
    k_init_misc<<<128, 256, 0, stream>>>(latent, Wz, bz, Ax, Az, bar);
    k_init_gx<<<16, 256, 0, stream>>>(W_ih, b_ih, b_hh, Gx);
    k_init_tok<<<64, 256, 0, stream>>>(seq, tok);
    k_init_wfrag<<<2048, 256, 0, stream>>>(W_hh, Bf);
    k_init_wfrag2<<<2048, 256, 0, stream>>>(Wnl, Bf2);
    k_recur<<<64, 512, 0, stream>>>(tok, Gx, Bf, Ax, bar);
    k_gemm1<<<dim3(16, 128), 256, 0, stream>>>(Ax, Az, Bf2, bnl, mid);
    k_loss<<<16384, 256, 0, stream>>>(mid, Wout, bout, labels, lengths, out);
    k_final<<<1, 1, 0, stream>>>(out);
}

// Round 5
// 2239.859 us; speedup vs baseline: 1.5668x; 1.5668x over previous
//
#include <hip/hip_runtime.h>
#include <hip/hip_bf16.h>

#define B_   32
#define T_   512
#define H_   1024
#define L_   256
#define V_   13
#define G4H  4096
#define KHL  1280   // H + L

typedef float f32x4 __attribute__((ext_vector_type(4)));
typedef short s16x8 __attribute__((ext_vector_type(8)));
typedef unsigned short u16;
typedef unsigned int   u32;
typedef unsigned long long u64;

// ---------------- ws layout (bytes) ----------------
// Ax  : u16 [1026][16384]    @ 0           (33,619,968)  h chain, MFMA frag layout
// Bf  : u16 [4,194,304]      @ 33,619,968  (8,388,608)   W_hh A-fragments
// Bf2 : u16 [1,310,720]      @ 42,008,576  (2,621,440)   Wnl  B-fragments
// Az  : u16 [2][4096]        @ 44,630,016  (16,384)      latent frag layout
// bar : int [2][512]         @ 44,646,400  (4,096)       flags: flag(mt,p) at
//                                                         mt*512 + p*16 (own line)
// mid : u16 [16384][1024]    @ 44,650,496  (33,554,432)
//   Gx (f32[57344]) and tok (u16[16384]) overlay mid (read only in k_recur).
#define OFF_BF   33619968u
#define OFF_BF2  42008576u
#define OFF_AZ   44630016u
#define OFF_BAR  44646400u
#define OFF_MID  44650496u
#define OFF_GX   OFF_MID                  // 229,376 B  = [jg][14][4] f32
#define OFF_TOK  (OFF_MID + 229376u)      //  32,768 B

__device__ __forceinline__ u16 f2bf(float f) {
    union { float f; u32 u; } v; v.f = f;
    u32 u = v.u;
    u32 r = (u + 0x7fffu + ((u >> 16) & 1u)) >> 16;   // RNE
    return (u16)r;
}
__device__ __forceinline__ float bf2f(u16 h) {
    union { u32 u; float f; } v; v.u = ((u32)h) << 16;
    return v.f;
}
__device__ __forceinline__ float sigm_(float x) {
    x = fminf(fmaxf(x, -30.f), 30.f);
    return 1.f / (1.f + __expf(-x));
}
__device__ __forceinline__ float tanh_(float x) {
    x = fminf(fmaxf(x, -15.f), 15.f);
    float e = __expf(2.f * x);
    return (e - 1.f) / (e + 1.f);
}

// fragment position of (lane-dim index bl, k) within a 16384-u16 slab
// (identical for MFMA A and B operands of 16x16x32)
__device__ __forceinline__ u32 afrag_pos(int bl, int k) {
    return (u32)((k >> 5) * 512 + ((bl | (((k >> 3) & 3) << 4)) << 3) + (k & 7));
}

// ---------------------------------------------------------------------------
__global__ __launch_bounds__(256) void k_init_misc(
        const float* __restrict__ latent, const float* __restrict__ Wz,
        const float* __restrict__ bz,
        u16* __restrict__ Ax, u16* __restrict__ Az, int* __restrict__ bar) {
    int gid = blockIdx.x * 256 + threadIdx.x;          // [0, 32768)
    int b = gid >> 10, j = gid & 1023;
    const float* lrow = latent + b * L_;
    const float* wrow = Wz + j * L_;
    float acc = bz[j];
    #pragma unroll 4
    for (int l = 0; l < L_; ++l) acc += lrow[l] * wrow[l];
    Ax[(b >> 4) * 16384 + afrag_pos(b & 15, j)] = f2bf(fmaxf(acc, 0.f));
    if (gid < B_ * L_) {
        int bb = gid >> 8, l = gid & 255;
        Az[(bb >> 4) * 4096 + afrag_pos(bb & 15, l)] = f2bf(latent[gid]);
    }
    if (gid < 1024) bar[gid] = 0;
}

// Gx[jg][t][gg] (t in [0,14), gg gate): W_ih[gg*H+jg][t] + b_ih + b_hh ; t=13 -> bias only
__global__ __launch_bounds__(256) void k_init_gx(
        const float* __restrict__ W_ih, const float* __restrict__ b_ih,
        const float* __restrict__ b_hh, float* __restrict__ Gx) {
    int row = blockIdx.x * 256 + threadIdx.x;          // [0,4096)
    if (row >= G4H) return;
    int gg = row >> 10, jg = row & 1023;
    float base = b_ih[row] + b_hh[row];
    float* d = Gx + (size_t)jg * 56;
    const float* wr = W_ih + (size_t)row * V_;
    #pragma unroll
    for (int t = 0; t < V_; ++t) d[t * 4 + gg] = base + wr[t];
    d[13 * 4 + gg] = base;
}

// tok[s*32+b] = one-hot index of seq[b,s,:] (13 if all-zero start row)
__global__ __launch_bounds__(256) void k_init_tok(
        const float* __restrict__ seq, u16* __restrict__ tok) {
    int gid = blockIdx.x * 256 + threadIdx.x;          // [0,16384)
    int s = gid >> 5, b = gid & 31;
    const float* r = seq + ((size_t)b * T_ + s) * V_;
    int t = 13;
    #pragma unroll
    for (int v = 0; v < V_; ++v) if (r[v] > 0.5f) t = v;
    tok[gid] = (u16)t;
}

// W_hh -> MFMA A-fragments. Tile col u = jj*4 + gate  (so C rows quad*4+r give
// all 4 gates of jj=quad in acc[r]). idx = (nt<<14)|(kc<<9)|(lane<<3)|jv.
// u = lane&15 -> gate = u&3, jj = u>>2 ; W row = gate*H + nt*4 + jj.
__global__ __launch_bounds__(256) void k_init_wfrag(
        const float* __restrict__ W_hh, u16* __restrict__ Bf) {
    int base = blockIdx.x * 256 + threadIdx.x;         // 2048 blocks
    #pragma unroll
    for (int i = 0; i < 8; ++i) {
        int idx = base + i * 524288;                   // [0, 4194304)
        int jv   = idx & 7;
        int lane = (idx >> 3) & 63;
        int kc   = (idx >> 9) & 31;
        int nt   = idx >> 14;
        int u = lane & 15;
        int row = (u & 3) * H_ + nt * 4 + (u >> 2);
        int k = kc * 32 + (lane >> 4) * 8 + jv;
        Bf[idx] = f2bf(W_hh[row * H_ + k]);
    }
}

__global__ __launch_bounds__(256) void k_init_wfrag2(
        const float* __restrict__ Wnl, u16* __restrict__ Bf2) {
    int idx = blockIdx.x * 256 + threadIdx.x;
    for (; idx < 1310720; idx += 524288) {
        int jv   = idx & 7;
        int lane = (idx >> 3) & 63;
        int q    = idx >> 9;                           // nt2*40 + kc
        int kc   = q % 40;
        int nt2  = q / 40;
        int n = nt2 * 16 + (lane & 15);
        int k = kc * 32 + (lane >> 4) * 8 + jv;
        Bf2[idx] = f2bf(Wnl[n * KHL + k]);
    }
}

// ---------------------------------------------------------------------------
// Persistent LSTM recurrence. 64 blocks x 512 thr (8 waves); mt = bid&1 picks
// the 16-batch group, p = bid>>1 is the producer index within the group.
// Sync protocol (NO atomic RMWs): each block owns flag(mt,p) on its own cache
// line, stores monotone value s+1 after its h chunk is drained. Wave 0 polls
// all 32 flags (lane i -> flag i) with relaxed LLC loads + __all ballot.
__global__ __launch_bounds__(512, 2) void k_recur(
        const u16* __restrict__ tokbuf, const float* __restrict__ Gx,
        const u16* __restrict__ Bf, u16* __restrict__ Ax,
        int* __restrict__ bar) {
    __shared__ u64 AhQ[4096];             // 32 KB h slab (frag layout)
    int tid = threadIdx.x;
    int bid = blockIdx.x;
    int mt = bid & 1;
    int p  = bid >> 1;                    // producer index [0,32)
    int w = tid >> 6, L = tid & 63;
    int nt = p * 8 + w;                   // [0,256)
    int lm = L & 15, quad = L >> 4;

    // W_hh A-fragments (compiler may keep in regs or re-fetch from L1/L2)
    s16x8 afr[32];
    {
        const u16* bfp = Bf + (size_t)nt * 16384 + L * 8;
        #pragma unroll
        for (int kc = 0; kc < 32; ++kc)
            afr[kc] = *reinterpret_cast<const s16x8*>(bfp + kc * 512);
    }
    int jg = nt * 4 + quad;               // this lane's output column
    int b = mt * 16 + lm;                 // this lane's batch
    const float* gxp = Gx + (size_t)jg * 56;
    u32 posu16 = (u32)((nt >> 3) * 512 + ((lm | (((nt >> 1) & 3) << 4)) << 3)
                       + (nt & 1) * 4 + quad);
    int* flags = bar + mt * 512;          // 32 flags, stride 16 dwords (64 B)
    u32* AxD = (u32*)Ax;
    const u64* AxQ = (const u64*)Ax;
    float c = 0.f;

    for (int s = 0; s < T_; ++s) {
        // wave 0: wait until all 32 producer flags reach s (slab s complete)
        if (w == 0) {
            const int* fp = flags + (L & 31) * 16;
            for (;;) {
                int v = __hip_atomic_load(fp, __ATOMIC_RELAXED,
                                          __HIP_MEMORY_SCOPE_AGENT);
                if (__all(v >= s)) break;
                __builtin_amdgcn_s_sleep(1);
            }
        }
        int tok = tokbuf[s * 32 + b];     // prefetch (L1/L2, independent)
        __syncthreads();
        asm volatile("" ::: "memory");

        // stage slab s (this mt) from LLC: 8 x u64 relaxed atomic loads/thread
        const u64* src = AxQ + ((size_t)s * 2 + mt) * 4096;
        #pragma unroll
        for (int k = 0; k < 8; ++k)
            AhQ[k * 512 + tid] = __hip_atomic_load(src + k * 512 + tid,
                __ATOMIC_RELAXED, __HIP_MEMORY_SCOPE_AGENT);
        float4 gx4 = *reinterpret_cast<const float4*>(gxp + tok * 4);
        __syncthreads();

        // gates tile: A = W frags, B = h frags (LDS); 4 independent chains
        f32x4 a0 = {0.f,0.f,0.f,0.f}, a1 = {0.f,0.f,0.f,0.f};
        f32x4 a2 = {0.f,0.f,0.f,0.f}, a3 = {0.f,0.f,0.f,0.f};
        const u16* hp = (const u16*)AhQ + L * 8;
        #pragma unroll
        for (int kc = 0; kc < 32; kc += 4) {
            s16x8 h0 = *reinterpret_cast<const s16x8*>(hp + kc * 512);
            s16x8 h1 = *reinterpret_cast<const s16x8*>(hp + (kc + 1) * 512);
            s16x8 h2 = *reinterpret_cast<const s16x8*>(hp + (kc + 2) * 512);
            s16x8 h3 = *reinterpret_cast<const s16x8*>(hp + (kc + 3) * 512);
            a0 = __builtin_amdgcn_mfma_f32_16x16x32_bf16(afr[kc],     h0, a0, 0, 0, 0);
            a1 = __builtin_amdgcn_mfma_f32_16x16x32_bf16(afr[kc + 1], h1, a1, 0, 0, 0);
            a2 = __builtin_amdgcn_mfma_f32_16x16x32_bf16(afr[kc + 2], h2, a2, 0, 0, 0);
            a3 = __builtin_amdgcn_mfma_f32_16x16x32_bf16(afr[kc + 3], h3, a3, 0, 0, 0);
        }
        // acc[r] = gate r (i,f,g,o) for (b, jg) — transpose-free
        float gi = a0[0] + a1[0] + a2[0] + a3[0] + gx4.x;
        float gf = a0[1] + a1[1] + a2[1] + a3[1] + gx4.y;
        float gg = a0[2] + a1[2] + a2[2] + a3[2] + gx4.z;
        float go = a0[3] + a1[3] + a2[3] + a3[3] + gx4.w;
        float ig = sigm_(gi), fg = sigm_(gf);
        float gt = tanh_(gg), og = sigm_(go);
        c = fg * c + ig * gt;
        float hv = og * tanh_(c);

        // write h(s+1): pack 2 bf16/dword, relaxed agent store -> LLC
        u32 bits = (u32)f2bf(hv);
        u32 other = (u32)(u16)__shfl_xor((int)bits, 16);
        if (!(quad & 1)) {
            u32 word = bits | (other << 16);
            __hip_atomic_store(
                AxD + ((size_t)(s + 1) * 2 + mt) * 8192 + (posu16 >> 1),
                word, __ATOMIC_RELAXED, __HIP_MEMORY_SCOPE_AGENT);
        }
        __syncthreads();                  // drains every wave's vmcnt

        if (s == T_ - 1) break;
        if (tid == 0)                     // publish: plain store to own line
            __hip_atomic_store(flags + p * 16, s + 1, __ATOMIC_RELAXED,
                               __HIP_MEMORY_SCOPE_AGENT);
    }
}

// ---------------------------------------------------------------------------
// mid = relu(feat @ Wnl^T + bnl) — A/B frags straight from global, no LDS.
__global__ __launch_bounds__(256) void k_gemm1(
        const u16* __restrict__ Ax, const u16* __restrict__ Az,
        const u16* __restrict__ Bf2, const float* __restrict__ bnl,
        u16* __restrict__ mid) {
    int tid = threadIdx.x;
    int nb = blockIdx.x;                  // [0,16)
    int mb = blockIdx.y;                  // [0,128)
    int w = tid >> 6, L = tid & 63;
    int lm = L & 15, quad = L >> 4;
    int mti0 = mb * 8 + w * 2;
    const u16* a0p = Ax + ((size_t)mti0 + 2) * 16384 + L * 8;
    const u16* a1p = a0p + 16384;
    const u16* az0 = Az + L * 8;
    const u16* az1 = az0 + 4096;
    const u16* bp = Bf2 + (size_t)(nb * 4) * 40 * 512 + L * 8;

    f32x4 acc[2][4];
    #pragma unroll
    for (int a = 0; a < 2; ++a)
        #pragma unroll
        for (int n = 0; n < 4; ++n) acc[a][n] = (f32x4){0.f, 0.f, 0.f, 0.f};

    #pragma unroll 4
    for (int kc = 0; kc < 32; ++kc) {
        s16x8 a0 = *reinterpret_cast<const s16x8*>(a0p + kc * 512);
        s16x8 a1 = *reinterpret_cast<const s16x8*>(a1p + kc * 512);
        #pragma unroll
        for (int n4 = 0; n4 < 4; ++n4) {
            s16x8 bv = *reinterpret_cast<const s16x8*>(bp + ((size_t)n4 * 40 + kc) * 512);
            acc[0][n4] = __builtin_amdgcn_mfma_f32_16x16x32_bf16(a0, bv, acc[0][n4], 0, 0, 0);
            acc[1][n4] = __builtin_amdgcn_mfma_f32_16x16x32_bf16(a1, bv, acc[1][n4], 0, 0, 0);
        }
    }
    #pragma unroll
    for (int kc2 = 0; kc2 < 8; ++kc2) {
        s16x8 a0 = *reinterpret_cast<const s16x8*>(az0 + kc2 * 512);
        s16x8 a1 = *reinterpret_cast<const s16x8*>(az1 + kc2 * 512);
        #pragma unroll
        for (int n4 = 0; n4 < 4; ++n4) {
            s16x8 bv = *reinterpret_cast<const s16x8*>(bp + ((size_t)n4 * 40 + 32 + kc2) * 512);
            acc[0][n4] = __builtin_amdgcn_mfma_f32_16x16x32_bf16(a0, bv, acc[0][n4], 0, 0, 0);
            acc[1][n4] = __builtin_amdgcn_mfma_f32_16x16x32_bf16(a1, bv, acc[1][n4], 0, 0, 0);
        }
    }
    #pragma unroll
    for (int mt2 = 0; mt2 < 2; ++mt2)
        #pragma unroll
        for (int n4 = 0; n4 < 4; ++n4)
            #pragma unroll
            for (int r = 0; r < 4; ++r) {
                int m = mb * 128 + w * 32 + mt2 * 16 + quad * 4 + r;
                int n = (nb * 4 + n4) * 16 + lm;
                float v = acc[mt2][n4][r] + bnl[n];
                mid[(size_t)m * H_ + n] = f2bf(fmaxf(v, 0.f));
            }
}

// ---------------------------------------------------------------------------
__global__ __launch_bounds__(256) void k_loss(
        const u16* __restrict__ mid, const float* __restrict__ Wout,
        const float* __restrict__ bout, const int* __restrict__ labels,
        const int* __restrict__ lengths, float* __restrict__ out) {
    int mrow = blockIdx.x;                // m = t*32 + b
    int b = mrow & 31, t = mrow >> 5;
    if (t >= lengths[b]) return;
    int tid = threadIdx.x;
    float p[V_];
    #pragma unroll
    for (int v = 0; v < V_; ++v) p[v] = 0.f;
    uint2 raw = *reinterpret_cast<const uint2*>(mid + (size_t)mrow * H_ + tid * 4);
    const u16* rs = (const u16*)&raw;
    float mv0 = bf2f(rs[0]), mv1 = bf2f(rs[1]), mv2 = bf2f(rs[2]), mv3 = bf2f(rs[3]);
    #pragma unroll
    for (int v = 0; v < V_; ++v) {
        float4 wv = *reinterpret_cast<const float4*>(Wout + v * H_ + tid * 4);
        p[v] = mv0 * wv.x + mv1 * wv.y + mv2 * wv.z + mv3 * wv.w;
    }
    #pragma unroll
    for (int off = 32; off > 0; off >>= 1)
        #pragma unroll
        for (int v = 0; v < V_; ++v) p[v] += __shfl_down(p[v], off);
    __shared__ float red[4][V_];
    int w = tid >> 6, L = tid & 63;
    if (L == 0)
        #pragma unroll
        for (int v = 0; v < V_; ++v) red[w][v] = p[v];
    __syncthreads();
    if (tid == 0) {
        float lg[V_]; float mx = -1e30f;
        #pragma unroll
        for (int v = 0; v < V_; ++v) {
            lg[v] = red[0][v] + red[1][v] + red[2][v] + red[3][v] + bout[v];
            mx = fmaxf(mx, lg[v]);
        }
        float se = 0.f;
        #pragma unroll
        for (int v = 0; v < V_; ++v) se += __expf(lg[v] - mx);
        float lse = mx + logf(se);
        int lab = labels[b * T_ + t];
        atomicAdd(&out[1 + b], lse - lg[lab]);
    }
}

__global__ void k_final(float* __restrict__ out) {
    float s = 0.f;
    for (int b = 0; b < B_; ++b) s += out[1 + b];
    out[0] = s;
}

// ---------------------------------------------------------------------------
extern "C" void kernel_launch(void* const* d_in, const int* in_sizes, int n_in,
                              void* d_out, int out_size, void* d_ws, size_t ws_size,
                              hipStream_t stream) {
    const float* seq    = (const float*)d_in[0];
    const float* latent = (const float*)d_in[1];
    const int*   labels = (const int*)d_in[2];
    const int*   lengths= (const int*)d_in[3];
    const float* W_ih   = (const float*)d_in[4];
    const float* W_hh   = (const float*)d_in[5];
    const float* b_ih   = (const float*)d_in[6];
    const float* b_hh   = (const float*)d_in[7];
    const float* Wz     = (const float*)d_in[8];
    const float* bz     = (const float*)d_in[9];
    const float* Wnl    = (const float*)d_in[10];
    const float* bnl    = (const float*)d_in[11];
    const float* Wout   = (const float*)d_in[12];
    const float* bout   = (const float*)d_in[13];

    char* ws = (char*)d_ws;
    u16*   Ax   = (u16*)(ws);
    u16*   Bf   = (u16*)(ws + OFF_BF);
    u16*   Bf2  = (u16*)(ws + OFF_BF2);
    u16*   Az   = (u16*)(ws + OFF_AZ);
    int*   bar  = (int*)(ws + OFF_BAR);
    u16*   mid  = (u16*)(ws + OFF_MID);
    float* Gx   = (float*)(ws + OFF_GX);
    u16*   tok  = (u16*)(ws + OFF_TOK);
    float* out  = (float*)d_out;

    hipMemsetAsync(d_out, 0, 33 * sizeof(float), stream);
    k_init_misc<<<128, 256, 0, stream>>>(latent, Wz, bz, Ax, Az, bar);
    k_init_gx<<<16, 256, 0, stream>>>(W_ih, b_ih, b_hh, Gx);
    k_init_tok<<<64, 256, 0, stream>>>(seq, tok);
    k_init_wfrag<<<2048, 256, 0, stream>>>(W_hh, Bf);
    k_init_wfrag2<<<2048, 256, 0, stream>>>(Wnl, Bf2);
    k_recur<<<64, 512, 0, stream>>>(tok, Gx, Bf, Ax, bar);
    k_gemm1<<<dim3(16, 128), 256, 0, stream>>>(Ax, Az, Bf2, bnl, mid);
    k_loss<<<16384, 256, 0, stream>>>(mid, Wout, bout, labels, lengths, out);
    k_final<<<1, 1, 0, stream>>>(out);
}

// Round 6
// 1483.062 us; speedup vs baseline: 2.3663x; 1.5103x over previous
//
#include <hip/hip_runtime.h>
#include <hip/hip_bf16.h>

#define B_   32
#define T_   512
#define H_   1024
#define L_   256
#define V_   13
#define G4H  4096
#define KHL  1280   // H + L

typedef float f32x4 __attribute__((ext_vector_type(4)));
typedef short s16x8 __attribute__((ext_vector_type(8)));
typedef unsigned short u16;
typedef unsigned int   u32;
typedef unsigned long long u64;

// ---------------- ws layout (bytes) ----------------
// Ax  : u16 [1026][16384]    @ 0           (33,619,968)  h chain, MFMA frag layout
//        slab (s,mt) at (s*2+mt)*32768 B; producer p's data = 1KB chunk p
// Bf  : u16 [4,194,304]      @ 33,619,968  (8,388,608)   W_hh A-fragments
// Bf2 : u16 [1,310,720]      @ 42,008,576  (2,621,440)   Wnl  B-fragments
// Az  : u16 [2][4096]        @ 44,630,016  (16,384)      latent frag layout
// bar : int [2][512]         @ 44,646,400  (4,096)       flag(mt,p) at mt*512+p*16
// mid : u16 [16384][1024]    @ 44,650,496  (33,554,432)
//   Gx (f32[57344]) and tok (u16[16384]) overlay mid (read only in k_recur).
#define OFF_BF   33619968u
#define OFF_BF2  42008576u
#define OFF_AZ   44630016u
#define OFF_BAR  44646400u
#define OFF_MID  44650496u
#define OFF_GX   OFF_MID                  // 229,376 B  = [jg][14][4] f32
#define OFF_TOK  (OFF_MID + 229376u)      //  32,768 B

__device__ __forceinline__ u16 f2bf(float f) {
    union { float f; u32 u; } v; v.f = f;
    u32 u = v.u;
    u32 r = (u + 0x7fffu + ((u >> 16) & 1u)) >> 16;   // RNE
    return (u16)r;
}
__device__ __forceinline__ float bf2f(u16 h) {
    union { u32 u; float f; } v; v.u = ((u32)h) << 16;
    return v.f;
}
__device__ __forceinline__ float sigm_(float x) {
    x = fminf(fmaxf(x, -30.f), 30.f);
    return 1.f / (1.f + __expf(-x));
}
__device__ __forceinline__ float tanh_(float x) {
    x = fminf(fmaxf(x, -15.f), 15.f);
    float e = __expf(2.f * x);
    return (e - 1.f) / (e + 1.f);
}

// fragment position of (lane-dim index bl, k) within a 16384-u16 slab
__device__ __forceinline__ u32 afrag_pos(int bl, int k) {
    return (u32)((k >> 5) * 512 + ((bl | (((k >> 3) & 3) << 4)) << 3) + (k & 7));
}

// ---------------------------------------------------------------------------
__global__ __launch_bounds__(256) void k_init_misc(
        const float* __restrict__ latent, const float* __restrict__ Wz,
        const float* __restrict__ bz,
        u16* __restrict__ Ax, u16* __restrict__ Az, int* __restrict__ bar) {
    int gid = blockIdx.x * 256 + threadIdx.x;          // [0, 32768)
    int b = gid >> 10, j = gid & 1023;
    const float* lrow = latent + b * L_;
    const float* wrow = Wz + j * L_;
    float acc = bz[j];
    #pragma unroll 4
    for (int l = 0; l < L_; ++l) acc += lrow[l] * wrow[l];
    Ax[(b >> 4) * 16384 + afrag_pos(b & 15, j)] = f2bf(fmaxf(acc, 0.f));
    if (gid < B_ * L_) {
        int bb = gid >> 8, l = gid & 255;
        Az[(bb >> 4) * 4096 + afrag_pos(bb & 15, l)] = f2bf(latent[gid]);
    }
    if (gid < 1024) bar[gid] = 0;
}

// Gx[jg][t][gg] (t in [0,14), gg gate): W_ih[gg*H+jg][t] + b_ih + b_hh ; t=13 -> bias only
__global__ __launch_bounds__(256) void k_init_gx(
        const float* __restrict__ W_ih, const float* __restrict__ b_ih,
        const float* __restrict__ b_hh, float* __restrict__ Gx) {
    int row = blockIdx.x * 256 + threadIdx.x;          // [0,4096)
    if (row >= G4H) return;
    int gg = row >> 10, jg = row & 1023;
    float base = b_ih[row] + b_hh[row];
    float* d = Gx + (size_t)jg * 56;
    const float* wr = W_ih + (size_t)row * V_;
    #pragma unroll
    for (int t = 0; t < V_; ++t) d[t * 4 + gg] = base + wr[t];
    d[13 * 4 + gg] = base;
}

// tok[s*32+b] = one-hot index of seq[b,s,:] (13 if all-zero start row)
__global__ __launch_bounds__(256) void k_init_tok(
        const float* __restrict__ seq, u16* __restrict__ tok) {
    int gid = blockIdx.x * 256 + threadIdx.x;          // [0,16384)
    int s = gid >> 5, b = gid & 31;
    const float* r = seq + ((size_t)b * T_ + s) * V_;
    int t = 13;
    #pragma unroll
    for (int v = 0; v < V_; ++v) if (r[v] > 0.5f) t = v;
    tok[gid] = (u16)t;
}

// W_hh -> MFMA A-fragments. Tile col u = jj*4 + gate.
__global__ __launch_bounds__(256) void k_init_wfrag(
        const float* __restrict__ W_hh, u16* __restrict__ Bf) {
    int base = blockIdx.x * 256 + threadIdx.x;         // 2048 blocks
    #pragma unroll
    for (int i = 0; i < 8; ++i) {
        int idx = base + i * 524288;                   // [0, 4194304)
        int jv   = idx & 7;
        int lane = (idx >> 3) & 63;
        int kc   = (idx >> 9) & 31;
        int nt   = idx >> 14;
        int u = lane & 15;
        int row = (u & 3) * H_ + nt * 4 + (u >> 2);
        int k = kc * 32 + (lane >> 4) * 8 + jv;
        Bf[idx] = f2bf(W_hh[row * H_ + k]);
    }
}

__global__ __launch_bounds__(256) void k_init_wfrag2(
        const float* __restrict__ Wnl, u16* __restrict__ Bf2) {
    int idx = blockIdx.x * 256 + threadIdx.x;
    for (; idx < 1310720; idx += 524288) {
        int jv   = idx & 7;
        int lane = (idx >> 3) & 63;
        int q    = idx >> 9;                           // nt2*40 + kc
        int kc   = q % 40;
        int nt2  = q / 40;
        int n = nt2 * 16 + (lane & 15);
        int k = kc * 32 + (lane >> 4) * 8 + jv;
        Bf2[idx] = f2bf(Wnl[n * KHL + k]);
    }
}

// ---------------------------------------------------------------------------
// Persistent LSTM recurrence. 64 blocks x 512 thr (8 waves); mt = bid&1 picks
// the 16-batch group, p = bid>>1 the producer index. Producer p's h output is
// the contiguous 1KB chunk p of the next slab. Wave w of every block consumes
// chunks {w, w+8, w+16, w+24}: it polls those 4 flags, then stages its 4KB
// with CACHEABLE uint4 loads (write-once addresses; flags order visibility).
__global__ __launch_bounds__(512, 1) void k_recur(
        const u16* __restrict__ tokbuf, const float* __restrict__ Gx,
        const u16* __restrict__ Bf, u16* __restrict__ Ax,
        int* __restrict__ bar) {
    __shared__ uint4 AhV[2048];           // 32 KB h slab (frag layout)
    int tid = threadIdx.x;
    int bid = blockIdx.x;
    int mt = bid & 1;
    int p  = bid >> 1;                    // producer index [0,32)
    int w = tid >> 6, L = tid & 63;
    int nt = p * 8 + w;                   // [0,256)
    int lm = L & 15, quad = L >> 4;

    // W_hh A-fragments -> registers (128 VGPR; bounds(512,1) allows ~512)
    s16x8 afr[32];
    {
        const u16* bfp = Bf + (size_t)nt * 16384 + L * 8;
        #pragma unroll
        for (int kc = 0; kc < 32; ++kc)
            afr[kc] = *reinterpret_cast<const s16x8*>(bfp + kc * 512);
    }
    int jg = nt * 4 + quad;               // this lane's output column
    int b = mt * 16 + lm;                 // this lane's batch
    const float* gxp = Gx + (size_t)jg * 56;
    u32 posu16 = (u32)((nt >> 3) * 512 + ((lm | (((nt >> 1) & 3) << 4)) << 3)
                       + (nt & 1) * 4 + quad);
    int* flags = bar + mt * 512;          // 32 flags, stride 16 dwords (64 B)
    const int* myflag = flags + (w + 8 * (L & 3)) * 16;   // this wave's 4 flags
    u32* AxD = (u32*)Ax;
    float c = 0.f;

    for (int s = 0; s < T_; ++s) {
        // prefetch x-term (independent of slab)
        int tok = tokbuf[s * 32 + b];
        float4 gx4 = *reinterpret_cast<const float4*>(gxp + tok * 4);

        // wave-local: wait for this wave's 4 producers to publish slab s
        for (;;) {
            int v = __hip_atomic_load(myflag, __ATOMIC_RELAXED,
                                      __HIP_MEMORY_SCOPE_AGENT);
            if (__all(v >= s)) break;
            __builtin_amdgcn_s_sleep(1);
        }
        // stage this wave's 4 chunks (i*8+w) with cacheable 16B loads
        const uint4* srcq = (const uint4*)((const char*)Ax
                             + ((size_t)s * 2 + mt) * 32768);
        #pragma unroll
        for (int i = 0; i < 4; ++i)
            AhV[i * 512 + tid] = srcq[i * 512 + tid];
        __syncthreads();                  // whole slab resident in LDS

        // gates tile: A = W frags (regs), B = h frags (LDS); 4 indep chains
        f32x4 a0 = {0.f,0.f,0.f,0.f}, a1 = {0.f,0.f,0.f,0.f};
        f32x4 a2 = {0.f,0.f,0.f,0.f}, a3 = {0.f,0.f,0.f,0.f};
        const u16* hp = (const u16*)AhV + L * 8;
        #pragma unroll
        for (int kc = 0; kc < 32; kc += 4) {
            s16x8 h0 = *reinterpret_cast<const s16x8*>(hp + kc * 512);
            s16x8 h1 = *reinterpret_cast<const s16x8*>(hp + (kc + 1) * 512);
            s16x8 h2 = *reinterpret_cast<const s16x8*>(hp + (kc + 2) * 512);
            s16x8 h3 = *reinterpret_cast<const s16x8*>(hp + (kc + 3) * 512);
            a0 = __builtin_amdgcn_mfma_f32_16x16x32_bf16(afr[kc],     h0, a0, 0, 0, 0);
            a1 = __builtin_amdgcn_mfma_f32_16x16x32_bf16(afr[kc + 1], h1, a1, 0, 0, 0);
            a2 = __builtin_amdgcn_mfma_f32_16x16x32_bf16(afr[kc + 2], h2, a2, 0, 0, 0);
            a3 = __builtin_amdgcn_mfma_f32_16x16x32_bf16(afr[kc + 3], h3, a3, 0, 0, 0);
        }
        // acc[r] = gate r (i,f,g,o) for (b, jg)
        float gi = a0[0] + a1[0] + a2[0] + a3[0] + gx4.x;
        float gf = a0[1] + a1[1] + a2[1] + a3[1] + gx4.y;
        float gg = a0[2] + a1[2] + a2[2] + a3[2] + gx4.z;
        float go = a0[3] + a1[3] + a2[3] + a3[3] + gx4.w;
        float ig = sigm_(gi), fg = sigm_(gf);
        float gt = tanh_(gg), og = sigm_(go);
        c = fg * c + ig * gt;
        float hv = og * tanh_(c);

        // write h(s+1): pack 2 bf16/dword, relaxed agent (LLC) store
        u32 bits = (u32)f2bf(hv);
        u32 other = (u32)(u16)__shfl_xor((int)bits, 16);
        if (!(quad & 1)) {
            u32 word = bits | (other << 16);
            __hip_atomic_store(
                AxD + ((size_t)(s + 1) * 2 + mt) * 8192 + (posu16 >> 1),
                word, __ATOMIC_RELAXED, __HIP_MEMORY_SCOPE_AGENT);
        }
        if (s == T_ - 1) break;           // final slab drains at kernel end
        __syncthreads();                  // drains all 8 waves' h stores
        if (tid == 0)                     // publish chunk p of slab s+1
            __hip_atomic_store(flags + p * 16, s + 1, __ATOMIC_RELAXED,
                               __HIP_MEMORY_SCOPE_AGENT);
    }
}

// ---------------------------------------------------------------------------
// mid = relu(feat @ Wnl^T + bnl) — A/B frags straight from global, no LDS.
__global__ __launch_bounds__(256) void k_gemm1(
        const u16* __restrict__ Ax, const u16* __restrict__ Az,
        const u16* __restrict__ Bf2, const float* __restrict__ bnl,
        u16* __restrict__ mid) {
    int tid = threadIdx.x;
    int nb = blockIdx.x;                  // [0,16)
    int mb = blockIdx.y;                  // [0,128)
    int w = tid >> 6, L = tid & 63;
    int lm = L & 15, quad = L >> 4;
    int mti0 = mb * 8 + w * 2;
    const u16* a0p = Ax + ((size_t)mti0 + 2) * 16384 + L * 8;
    const u16* a1p = a0p + 16384;
    const u16* az0 = Az + L * 8;
    const u16* az1 = az0 + 4096;
    const u16* bp = Bf2 + (size_t)(nb * 4) * 40 * 512 + L * 8;

    f32x4 acc[2][4];
    #pragma unroll
    for (int a = 0; a < 2; ++a)
        #pragma unroll
        for (int n = 0; n < 4; ++n) acc[a][n] = (f32x4){0.f, 0.f, 0.f, 0.f};

    #pragma unroll 4
    for (int kc = 0; kc < 32; ++kc) {
        s16x8 a0 = *reinterpret_cast<const s16x8*>(a0p + kc * 512);
        s16x8 a1 = *reinterpret_cast<const s16x8*>(a1p + kc * 512);
        #pragma unroll
        for (int n4 = 0; n4 < 4; ++n4) {
            s16x8 bv = *reinterpret_cast<const s16x8*>(bp + ((size_t)n4 * 40 + kc) * 512);
            acc[0][n4] = __builtin_amdgcn_mfma_f32_16x16x32_bf16(a0, bv, acc[0][n4], 0, 0, 0);
            acc[1][n4] = __builtin_amdgcn_mfma_f32_16x16x32_bf16(a1, bv, acc[1][n4], 0, 0, 0);
        }
    }
    #pragma unroll
    for (int kc2 = 0; kc2 < 8; ++kc2) {
        s16x8 a0 = *reinterpret_cast<const s16x8*>(az0 + kc2 * 512);
        s16x8 a1 = *reinterpret_cast<const s16x8*>(az1 + kc2 * 512);
        #pragma unroll
        for (int n4 = 0; n4 < 4; ++n4) {
            s16x8 bv = *reinterpret_cast<const s16x8*>(bp + ((size_t)n4 * 40 + 32 + kc2) * 512);
            acc[0][n4] = __builtin_amdgcn_mfma_f32_16x16x32_bf16(a0, bv, acc[0][n4], 0, 0, 0);
            acc[1][n4] = __builtin_amdgcn_mfma_f32_16x16x32_bf16(a1, bv, acc[1][n4], 0, 0, 0);
        }
    }
    #pragma unroll
    for (int mt2 = 0; mt2 < 2; ++mt2)
        #pragma unroll
        for (int n4 = 0; n4 < 4; ++n4)
            #pragma unroll
            for (int r = 0; r < 4; ++r) {
                int m = mb * 128 + w * 32 + mt2 * 16 + quad * 4 + r;
                int n = (nb * 4 + n4) * 16 + lm;
                float v = acc[mt2][n4][r] + bnl[n];
                mid[(size_t)m * H_ + n] = f2bf(fmaxf(v, 0.f));
            }
}

// ---------------------------------------------------------------------------
__global__ __launch_bounds__(256) void k_loss(
        const u16* __restrict__ mid, const float* __restrict__ Wout,
        const float* __restrict__ bout, const int* __restrict__ labels,
        const int* __restrict__ lengths, float* __restrict__ out) {
    int mrow = blockIdx.x;                // m = t*32 + b
    int b = mrow & 31, t = mrow >> 5;
    if (t >= lengths[b]) return;
    int tid = threadIdx.x;
    float p[V_];
    #pragma unroll
    for (int v = 0; v < V_; ++v) p[v] = 0.f;
    uint2 raw = *reinterpret_cast<const uint2*>(mid + (size_t)mrow * H_ + tid * 4);
    const u16* rs = (const u16*)&raw;
    float mv0 = bf2f(rs[0]), mv1 = bf2f(rs[1]), mv2 = bf2f(rs[2]), mv3 = bf2f(rs[3]);
    #pragma unroll
    for (int v = 0; v < V_; ++v) {
        float4 wv = *reinterpret_cast<const float4*>(Wout + v * H_ + tid * 4);
        p[v] = mv0 * wv.x + mv1 * wv.y + mv2 * wv.z + mv3 * wv.w;
    }
    #pragma unroll
    for (int off = 32; off > 0; off >>= 1)
        #pragma unroll
        for (int v = 0; v < V_; ++v) p[v] += __shfl_down(p[v], off);
    __shared__ float red[4][V_];
    int w = tid >> 6, L = tid & 63;
    if (L == 0)
        #pragma unroll
        for (int v = 0; v < V_; ++v) red[w][v] = p[v];
    __syncthreads();
    if (tid == 0) {
        float lg[V_]; float mx = -1e30f;
        #pragma unroll
        for (int v = 0; v < V_; ++v) {
            lg[v] = red[0][v] + red[1][v] + red[2][v] + red[3][v] + bout[v];
            mx = fmaxf(mx, lg[v]);
        }
        float se = 0.f;
        #pragma unroll
        for (int v = 0; v < V_; ++v) se += __expf(lg[v] - mx);
        float lse = mx + logf(se);
        int lab = labels[b * T_ + t];
        atomicAdd(&out[1 + b], lse - lg[lab]);
    }
}

__global__ void k_final(float* __restrict__ out) {
    float s = 0.f;
    for (int b = 0; b < B_; ++b) s += out[1 + b];
    out[0] = s;
}

// ---------------------------------------------------------------------------
extern "C" void kernel_launch(void* const* d_in, const int* in_sizes, int n_in,
                              void* d_out, int out_size, void* d_ws, size_t ws_size,
                              hipStream_t stream) {
    const float* seq    = (const float*)d_in[0];
    const float* latent = (const float*)d_in[1];
    const int*   labels = (const int*)d_in[2];
    const int*   lengths= (const int*)d_in[3];
    const float* W_ih   = (const float*)d_in[4];
    const float* W_hh   = (const float*)d_in[5];
    const float* b_ih   = (const float*)d_in[6];
    const float* b_hh   = (const float*)d_in[7];
    const float* Wz     = (const float*)d_in[8];
    const float* bz     = (const float*)d_in[9];
    const float* Wnl    = (const float*)d_in[10];
    const float* bnl    = (const float*)d_in[11];
    const float* Wout   = (const float*)d_in[12];
    const float* bout   = (const float*)d_in[13];

    char* ws = (char*)d_ws;
    u16*   Ax   = (u16*)(ws);
    u16*   Bf   = (u16*)(ws + OFF_BF);
    u16*   Bf2  = (u16*)(ws + OFF_BF2);
    u16*   Az   = (u16*)(ws + OFF_AZ);
    int*   bar  = (int*)(ws + OFF_BAR);
    u16*   mid  = (u16*)(ws + OFF_MID);
    float* Gx   = (float*)(ws + OFF_GX);
    u16*   tok  = (u16*)(ws + OFF_TOK);
    float* out  = (float*)d_out;

    hipMemsetAsync(d_out, 0, 33 * sizeof(float), stream);
    k_init_misc<<<128, 256, 0, stream>>>(latent, Wz, bz, Ax, Az, bar);
    k_init_gx<<<16, 256, 0, stream>>>(W_ih, b_ih, b_hh, Gx);
    k_init_tok<<<64, 256, 0, stream>>>(seq, tok);
    k_init_wfrag<<<2048, 256, 0, stream>>>(W_hh, Bf);
    k_init_wfrag2<<<2048, 256, 0, stream>>>(Wnl, Bf2);
    k_recur<<<64, 512, 0, stream>>>(tok, Gx, Bf, Ax, bar);
    k_gemm1<<<dim3(16, 128), 256, 0, stream>>>(Ax, Az, Bf2, bnl, mid);
    k_loss<<<16384, 256, 0, stream>>>(mid, Wout, bout, labels, lengths, out);
    k_final<<<1, 1, 0, stream>>>(out);
}